// Round 14
// baseline (229.783 us; speedup 1.0000x reference)
//
#include <hip/hip_runtime.h>
#include <hip/hip_bf16.h>
#include <stdint.h>

#define HN 128      // hidden size
#define TSTEPS 250
#define ON 20       // output size
#define GK 700      // input size
#define NKT 22      // GEMM k-tiles of 32 (700 = 21*32 + 28, zero-padded)

typedef _Float16 h2 __attribute__((ext_vector_type(2)));
typedef _Float16 h8 __attribute__((ext_vector_type(8)));
typedef float f4 __attribute__((ext_vector_type(4)));

__device__ __forceinline__ uint32_t pack2u(float x, float y) {
    h2 p; p.x = (_Float16)x; p.y = (_Float16)y;
    return __builtin_bit_cast(uint32_t, p);
}

// ---------------------------------------------------------------------------
// Phase A: in1_ff[bt,h] = X[bt,:] . W_ih1[h,:] + b_ih1[h]
// M=64000, N=128, K=700(pad 704). f16 MFMA 16x16x32 (verified r12).
// ---------------------------------------------------------------------------
__global__ __launch_bounds__(256) void ff_gemm(const float* __restrict__ X,
                                               const float* __restrict__ W,
                                               const float* __restrict__ bias,
                                               float* __restrict__ out) {
    __shared__ __align__(16) uint32_t Xs[2][128][16];   // 8 KB x2 (f16 pairs)
    __shared__ __align__(16) uint32_t Ws[2][128][16];   // 8 KB x2
    const int tid   = threadIdx.x;
    const int w     = tid >> 6;
    const int lane  = tid & 63;
    const int m0    = blockIdx.x * 128;
    const int srow  = tid & 127;
    const int shalf = tid >> 7;
    const int lr    = lane & 15;
    const int lg    = lane >> 4;

    f4 acc[2][8];
#pragma unroll
    for (int m = 0; m < 2; ++m)
#pragma unroll
        for (int n = 0; n < 8; ++n) acc[m][n] = (f4){0.f, 0.f, 0.f, 0.f};

    float4 x4[4], w4[4];

#define LOADT(t)                                                               \
    {                                                                          \
        const int k0 = (t) * 32 + shalf * 16;                                  \
        if ((t) < 21 || shalf == 0) {                                          \
            _Pragma("unroll")                                                  \
            for (int q = 0; q < 4; ++q) {                                      \
                x4[q] = *(const float4*)&X[(size_t)(m0 + srow) * GK + k0 + q * 4]; \
                w4[q] = *(const float4*)&W[(size_t)srow * GK + k0 + q * 4];    \
            }                                                                  \
        } else {                                                               \
            _Pragma("unroll")                                                  \
            for (int q = 0; q < 3; ++q) {                                      \
                x4[q] = *(const float4*)&X[(size_t)(m0 + srow) * GK + k0 + q * 4]; \
                w4[q] = *(const float4*)&W[(size_t)srow * GK + k0 + q * 4];    \
            }                                                                  \
            x4[3] = (float4){0.f, 0.f, 0.f, 0.f};                              \
            w4[3] = (float4){0.f, 0.f, 0.f, 0.f};                              \
        }                                                                      \
    }
#define STORET(buf)                                                            \
    {                                                                          \
        _Pragma("unroll")                                                      \
        for (int q = 0; q < 4; ++q) {                                          \
            Xs[buf][srow][shalf * 8 + 2 * q]     = pack2u(x4[q].x, x4[q].y);   \
            Xs[buf][srow][shalf * 8 + 2 * q + 1] = pack2u(x4[q].z, x4[q].w);   \
            Ws[buf][srow][shalf * 8 + 2 * q]     = pack2u(w4[q].x, w4[q].y);   \
            Ws[buf][srow][shalf * 8 + 2 * q + 1] = pack2u(w4[q].z, w4[q].w);   \
        }                                                                      \
    }

    LOADT(0);
    STORET(0);
    __syncthreads();
    int cur = 0;
    for (int t = 0; t < NKT; ++t) {
        if (t + 1 < NKT) LOADT(t + 1);
        h8 a[2];
#pragma unroll
        for (int m = 0; m < 2; ++m) {
            const uint4 au = *(const uint4*)&Xs[cur][w * 32 + m * 16 + lr][lg * 4];
            a[m] = __builtin_bit_cast(h8, au);
        }
#pragma unroll
        for (int n = 0; n < 8; ++n) {
            const uint4 bu = *(const uint4*)&Ws[cur][n * 16 + lr][lg * 4];
            const h8 bf = __builtin_bit_cast(h8, bu);
            acc[0][n] = __builtin_amdgcn_mfma_f32_16x16x32_f16(a[0], bf, acc[0][n], 0, 0, 0);
            acc[1][n] = __builtin_amdgcn_mfma_f32_16x16x32_f16(a[1], bf, acc[1][n], 0, 0, 0);
        }
        if (t + 1 < NKT) STORET(cur ^ 1);
        __syncthreads();
        cur ^= 1;
    }

    float bv[8];
#pragma unroll
    for (int n = 0; n < 8; ++n) bv[n] = bias[n * 16 + lr];
#pragma unroll
    for (int m = 0; m < 2; ++m)
#pragma unroll
        for (int q = 0; q < 4; ++q) {
            const size_t row = (size_t)(m0 + w * 32 + m * 16 + lg * 4 + q);
#pragma unroll
            for (int n = 0; n < 8; ++n)
                out[row * HN + n * 16 + lr] = acc[m][n][q] + bv[n];
        }
#undef LOADT
#undef STORET
}

// ---------------------------------------------------------------------------
// i8 matvec helpers: weights WQ[g][j] = uint4 of 16 i8 (k = 16g..16g+15);
// spike vector sv[8] wave-uniform packed 0/1 bytes.
// 8 conflict-free ds_read_b128 + 32 v_dot4 in 4 independent chains.
// ---------------------------------------------------------------------------
__device__ __forceinline__ int mvq(const uint4 (&W)[8][HN],
                                   const uint4 (&sv)[8], int j) {
    int a0 = 0, a1 = 0, a2 = 0, a3 = 0;
#pragma unroll
    for (int g = 0; g < 8; ++g) {
        const uint4 wq = W[g][j];
        const uint4 sq = sv[g];
        a0 = __builtin_amdgcn_sdot4((int)wq.x, (int)sq.x, a0, false);
        a1 = __builtin_amdgcn_sdot4((int)wq.y, (int)sq.y, a1, false);
        a2 = __builtin_amdgcn_sdot4((int)wq.z, (int)sq.z, a2, false);
        a3 = __builtin_amdgcn_sdot4((int)wq.w, (int)sq.w, a3, false);
    }
    return (a0 + a1) + (a2 + a3);
}
__device__ __forceinline__ int mvqo(const uint4 (&W)[8][32],
                                    const uint4 (&sv)[8], int j) {
    int a0 = 0, a1 = 0, a2 = 0, a3 = 0;
#pragma unroll
    for (int g = 0; g < 8; ++g) {
        const uint4 wq = W[g][j];
        const uint4 sq = sv[g];
        a0 = __builtin_amdgcn_sdot4((int)wq.x, (int)sq.x, a0, false);
        a1 = __builtin_amdgcn_sdot4((int)wq.y, (int)sq.y, a1, false);
        a2 = __builtin_amdgcn_sdot4((int)wq.z, (int)sq.z, a2, false);
        a3 = __builtin_amdgcn_sdot4((int)wq.w, (int)sq.w, a3, false);
    }
    return (a0 + a1) + (a2 + a3);
}

#define LOADQ(arr, buf, sv)                                                    \
    {                                                                          \
        const uint4* _p = (const uint4*)&arr[buf][0];                          \
        _Pragma("unroll") for (int _g = 0; _g < 8; ++_g) sv[_g] = _p[_g];      \
    }

// ballot-mask nibble -> 4 packed 0/1 bytes
__device__ __forceinline__ uint32_t nib2bytes(uint32_t nib) {
    return ((nib & 15u) * 0x00204081u) & 0x01010101u;
}

// ---------------------------------------------------------------------------
// Phase B: i8-LDS sdot4 pipeline, 6 heavy waves. One WG (512 thr) per batch
// row. Per-row i8 quantized weights in LDS; spikes packed 0/1 bytes via
// __ballot (no shfl). OM wave: fully redundant per-lane register softmax
// (zero cross-lane ops -> no longer the barrier straggler). Roles (slot i):
//   w0,w1: S1 -> s1(i)   w2,w3: B -> pB(i-1)   w4,w5: C+L2 -> s2(i-2)
//   w6: RO -> rdot(i-3)  w7: OM -> om/softmax(i-4)
// ---------------------------------------------------------------------------
__global__ __launch_bounds__(512) void srnn_pipe10(
    const float* __restrict__ ff,
    const float* __restrict__ W_h1h1, const float* __restrict__ b_h1h1,
    const float* __restrict__ W_h1h2, const float* __restrict__ b_h1h2,
    const float* __restrict__ W_h2h2, const float* __restrict__ b_h2h2,
    const float* __restrict__ W_h2o,  const float* __restrict__ b_h2o,
    const float* __restrict__ tau_adp_h1, const float* __restrict__ tau_adp_h2,
    const float* __restrict__ tau_m_h1,   const float* __restrict__ tau_m_h2,
    const float* __restrict__ tau_m_o,
    const float* __restrict__ h1m0, const float* __restrict__ h2m0,
    const float* __restrict__ om0,
    float* __restrict__ out) {
    const int b    = blockIdx.x;
    const int tid  = threadIdx.x;
    const int w    = tid >> 6;
    const int lane = tid & 63;

    __shared__ __align__(16) uint4 WQA[8][HN];   // 16 KB
    __shared__ __align__(16) uint4 WQB[8][HN];   // 16 KB
    __shared__ __align__(16) uint4 WQC[8][HN];   // 16 KB
    __shared__ __align__(16) uint4 WQO[8][32];   //  4 KB
    __shared__ float scA[HN], scB[HN], scC[HN], scO[32];
    __shared__ __align__(16) uint32_t s1w[2][32];
    __shared__ __align__(16) uint32_t s2w[2][32];
    __shared__ float pBbuf[2][HN];
    __shared__ __align__(16) float rdot_lds[2][32];

    // ---- stage: per-row i8 quantization (one time) ----
    if (tid < 416) {
        const int role = tid >> 7;          // 0:A 1:B 2:C 3:O-block
        const int j    = tid & 127;
        const bool isO = (role == 3);
        const bool on  = !isO || (j < 32);
        if (on) {
            const float* src = nullptr;
            bool valid = true;
            if (!isO) {
                src = (role == 0 ? W_h1h1 : role == 1 ? W_h1h2 : W_h2h2) + j * HN;
            } else if (j < ON) {
                src = W_h2o + j * HN;
            } else {
                valid = false;
            }
            float amax = 0.f;
            if (valid) {
#pragma unroll
                for (int q = 0; q < 32; ++q) {
                    float4 v = *(const float4*)&src[q * 4];
                    amax = fmaxf(amax, fmaxf(fmaxf(fabsf(v.x), fabsf(v.y)),
                                             fmaxf(fabsf(v.z), fabsf(v.w))));
                }
            }
            const float qs = (valid && amax > 0.f) ? 127.f / amax : 0.f;
#pragma unroll
            for (int g = 0; g < 8; ++g) {
                uint32_t u[4] = {0u, 0u, 0u, 0u};
                if (valid) {
#pragma unroll
                    for (int e = 0; e < 4; ++e) {
                        float4 v = *(const float4*)&src[g * 16 + e * 4];
                        const int q0 = (int)rintf(v.x * qs), q1 = (int)rintf(v.y * qs);
                        const int q2 = (int)rintf(v.z * qs), q3 = (int)rintf(v.w * qs);
                        u[e] = (uint32_t)(q0 & 255) | ((uint32_t)(q1 & 255) << 8) |
                               ((uint32_t)(q2 & 255) << 16) | ((uint32_t)(q3 & 255) << 24);
                    }
                }
                uint4 w4; w4.x = u[0]; w4.y = u[1]; w4.z = u[2]; w4.w = u[3];
                if (isO) WQO[g][j] = w4;
                else if (role == 0) WQA[g][j] = w4;
                else if (role == 1) WQB[g][j] = w4;
                else WQC[g][j] = w4;
            }
            const float os = (valid && amax > 0.f) ? amax / 127.f : 0.f;
            if (isO) scO[j] = os;
            else if (role == 0) scA[j] = os;
            else if (role == 1) scB[j] = os;
            else scC[j] = os;
        }
    }
    if (tid < 32) {
        s1w[0][tid] = 0u; s1w[1][tid] = 0u;
        s2w[0][tid] = 0u; s2w[1][tid] = 0u;
    }
    __syncthreads();

    if (w < 2) {
        // ================= S1: layer-1 LIF, j = w*64+lane =================
        const int j = (w << 6) + lane;
        const float sA = scA[j];
        float h1m = h1m0[b * HN + j];
        const float a1 = expf(-1.f / tau_m_h1[j]);
        const float r1 = expf(-1.f / tau_adp_h1[j]);
        const float bi = b_h1h1[j];
        float b1 = 0.01f, s1p = 0.f;
        const float* fp = ff + (size_t)b * TSTEPS * HN + j;
        float fc = fp[0], fn = fp[HN];
        for (int i = 0; i < TSTEPS + 4; ++i) {
            if (i < TSTEPS) {
                const float f2 = (i + 2 < TSTEPS) ? fp[(size_t)(i + 2) * HN] : 0.f;
                uint4 sv[8];
                LOADQ(s1w, (i + 1) & 1, sv);               // s1(i-1)
                const float pA = sA * (float)mvq(WQA, sv, j);
                b1 = r1 * b1 + (1.f - r1) * s1p;
                const float Bt = 0.01f + 1.8f * b1;
                h1m = h1m * a1 + (1.f - a1) * (fc + bi + pA) - Bt * s1p;
                const int sp = (h1m - Bt > 0.f) ? 1 : 0;
                s1p = (float)sp;
                const unsigned long long mk = __ballot(sp);
                const uint32_t mlo = (uint32_t)mk, mhi = (uint32_t)(mk >> 32);
                if (lane < 16) {
                    const uint32_t nib = (lane < 8 ? mlo : mhi) >> ((lane & 7) * 4);
                    s1w[i & 1][(w << 4) + lane] = nib2bytes(nib);
                }
                fc = fn; fn = f2;
            }
            __syncthreads();
        }
    } else if (w < 4) {
        // ================= B: pB(i-1) = W_h1h2 . s1(i-1) =================
        const int j = ((w - 2) << 6) + lane;
        const float sB = scB[j];
        for (int i = 0; i < TSTEPS + 4; ++i) {
            if (i >= 1 && i <= TSTEPS) {
                uint4 sv[8];
                LOADQ(s1w, (i - 1) & 1, sv);
                pBbuf[(i - 1) & 1][j] = sB * (float)mvq(WQB, sv, j);
            }
            __syncthreads();
        }
    } else if (w < 6) {
        // ================= C + LIF2: s2(i-2), j = (w-4)*64+lane ============
        const int j = ((w - 4) << 6) + lane;
        const float sC = scC[j];
        float h2m = h2m0[b * HN + j];
        const float a2 = expf(-1.f / tau_m_h2[j]);
        const float r2 = expf(-1.f / tau_adp_h2[j]);
        const float bi = b_h1h2[j] + b_h2h2[j];
        float b2v = 0.01f, s2p = 0.f;
        for (int i = 0; i < TSTEPS + 4; ++i) {
            if (i >= 2 && i <= TSTEPS + 1) {
                const int k2 = i - 2;
                uint4 sv[8];
                LOADQ(s2w, (k2 + 1) & 1, sv);              // s2(k2-1)
                const float pC = sC * (float)mvq(WQC, sv, j);
                const float in2 = pBbuf[k2 & 1][j] + pC + bi;
                b2v = r2 * b2v + (1.f - r2) * s2p;
                const float Bt = 0.01f + 1.8f * b2v;
                h2m = h2m * a2 + (1.f - a2) * in2 - Bt * s2p;
                const int sp = (h2m - Bt > 0.f) ? 1 : 0;
                s2p = (float)sp;
                const unsigned long long mk = __ballot(sp);
                const uint32_t mlo = (uint32_t)mk, mhi = (uint32_t)(mk >> 32);
                if (lane < 16) {
                    const uint32_t nib = (lane < 8 ? mlo : mhi) >> ((lane & 7) * 4);
                    s2w[k2 & 1][((w - 4) << 4) + lane] = nib2bytes(nib);
                }
            }
            __syncthreads();
        }
    } else if (w == 6) {
        // ================= RO: rdot(i-3) = W_h2o . s2(i-3) =================
        const int o = lane;
        const float sO = (o < 32) ? scO[o] : 0.f;
        for (int i = 0; i < TSTEPS + 4; ++i) {
            if (i >= 3 && i <= TSTEPS + 2 && o < ON) {
                const int k3 = i - 3;
                uint4 sv[8];
                LOADQ(s2w, k3 & 1, sv);
                rdot_lds[k3 & 1][o] = sO * (float)mvqo(WQO, sv, o);
            }
            __syncthreads();
        }
    } else {
        // ================= OM: redundant register softmax, no cross-lane ===
        float omv[ON], accv[ON], aov[ON], bov[ON];
#pragma unroll
        for (int k = 0; k < ON; ++k) {
            omv[k]  = om0[b * ON + k];
            aov[k]  = expf(-1.f / tau_m_o[k]);
            bov[k]  = b_h2o[k];
            accv[k] = 0.f;
        }
        for (int i = 0; i < TSTEPS + 4; ++i) {
            if (i >= 4) {
                const int k4 = i - 4;
                const float4* rp = (const float4*)&rdot_lds[k4 & 1][0];
                const float4 r0 = rp[0], r1 = rp[1], r2 = rp[2], r3 = rp[3], r4 = rp[4];
                float rd[ON];
                rd[0] = r0.x;  rd[1] = r0.y;  rd[2] = r0.z;  rd[3] = r0.w;
                rd[4] = r1.x;  rd[5] = r1.y;  rd[6] = r1.z;  rd[7] = r1.w;
                rd[8] = r2.x;  rd[9] = r2.y;  rd[10] = r2.z; rd[11] = r2.w;
                rd[12] = r3.x; rd[13] = r3.y; rd[14] = r3.z; rd[15] = r3.w;
                rd[16] = r4.x; rd[17] = r4.y; rd[18] = r4.z; rd[19] = r4.w;
#pragma unroll
                for (int k = 0; k < ON; ++k)
                    omv[k] = omv[k] * aov[k] + (1.f - aov[k]) * (rd[k] + bov[k]);
                // max: 4 parallel chains
                float m0 = omv[0], m1 = omv[1], m2 = omv[2], m3 = omv[3];
#pragma unroll
                for (int k = 4; k < ON; k += 4) {
                    m0 = fmaxf(m0, omv[k]);
                    m1 = fmaxf(m1, omv[k + 1]);
                    m2 = fmaxf(m2, omv[k + 2]);
                    m3 = fmaxf(m3, omv[k + 3]);
                }
                const float mx = fmaxf(fmaxf(m0, m1), fmaxf(m2, m3));
                float e[ON];
                float d0 = 0.f, d1 = 0.f, d2 = 0.f, d3 = 0.f;
#pragma unroll
                for (int k = 0; k < ON; k += 4) {
                    e[k]     = __expf(omv[k] - mx);     d0 += e[k];
                    e[k + 1] = __expf(omv[k + 1] - mx); d1 += e[k + 1];
                    e[k + 2] = __expf(omv[k + 2] - mx); d2 += e[k + 2];
                    e[k + 3] = __expf(omv[k + 3] - mx); d3 += e[k + 3];
                }
                const float den = (d0 + d1) + (d2 + d3);
                if (k4 > 10) {
                    const float rden = 1.f / den;
#pragma unroll
                    for (int k = 0; k < ON; ++k)
                        accv[k] = fmaf(e[k], rden, accv[k]);
                }
            }
            __syncthreads();
        }
        if (lane == 0) {
#pragma unroll
            for (int k = 0; k < ON; ++k) out[b * ON + k] = accv[k];
        }
    }
}

// ---------------------------------------------------------------------------
// Phase C: A_norm = sum|W_h1h1| + sum|W_h2h2|  -> out[5120]  (exact fp32)
// ---------------------------------------------------------------------------
__global__ void anorm_kernel(const float* __restrict__ W1,
                             const float* __restrict__ W2,
                             float* __restrict__ out) {
    __shared__ float red[256];
    float s = 0.f;
    for (int i = threadIdx.x; i < HN * HN; i += 256)
        s += fabsf(W1[i]) + fabsf(W2[i]);
    red[threadIdx.x] = s;
    __syncthreads();
    for (int off = 128; off > 0; off >>= 1) {
        if (threadIdx.x < off) red[threadIdx.x] += red[threadIdx.x + off];
        __syncthreads();
    }
    if (threadIdx.x == 0) out[256 * ON] = red[0];
}

extern "C" void kernel_launch(void* const* d_in, const int* in_sizes, int n_in,
                              void* d_out, int out_size, void* d_ws, size_t ws_size,
                              hipStream_t stream) {
    const float* input      = (const float*)d_in[0];
    // d_in[1], d_in[2]: A1_mask/A2_mask -- all-ones, unused by reference math
    const float* W_ih1      = (const float*)d_in[3];
    const float* b_ih1      = (const float*)d_in[4];
    const float* W_h1h1     = (const float*)d_in[5];
    const float* b_h1h1     = (const float*)d_in[6];
    const float* W_h1h2     = (const float*)d_in[7];
    const float* b_h1h2     = (const float*)d_in[8];
    const float* W_h2h2     = (const float*)d_in[9];
    const float* b_h2h2     = (const float*)d_in[10];
    const float* W_h2o      = (const float*)d_in[11];
    const float* b_h2o      = (const float*)d_in[12];
    const float* tau_adp_h1 = (const float*)d_in[13];
    const float* tau_adp_h2 = (const float*)d_in[14];
    const float* tau_m_h1   = (const float*)d_in[15];
    const float* tau_m_h2   = (const float*)d_in[16];
    const float* tau_m_o    = (const float*)d_in[17];
    const float* h1m0       = (const float*)d_in[18];
    const float* h2m0       = (const float*)d_in[19];
    const float* om0        = (const float*)d_in[20];

    float* out   = (float*)d_out;
    float* ffbuf = (float*)d_ws;   // 256*250*128*4 = 32.768 MB

    anorm_kernel<<<1, 256, 0, stream>>>(W_h1h1, W_h2h2, out);
    ff_gemm<<<500, 256, 0, stream>>>(input, W_ih1, b_ih1, ffbuf);
    srnn_pipe10<<<256, 512, 0, stream>>>(ffbuf, W_h1h1, b_h1h1, W_h1h2, b_h1h2,
                                         W_h2h2, b_h2h2, W_h2o, b_h2o,
                                         tau_adp_h1, tau_adp_h2,
                                         tau_m_h1, tau_m_h2, tau_m_o,
                                         h1m0, h2m0, om0, out);
}

// Round 15
// 224.888 us; speedup vs baseline: 1.0218x; 1.0218x over previous
//
#include <hip/hip_runtime.h>
#include <hip/hip_bf16.h>
#include <stdint.h>

#define HN 128      // hidden size
#define TSTEPS 250
#define ON 20       // output size
#define GK 700      // input size
#define NKT 22      // GEMM k-tiles of 32 (700 = 21*32 + 28, zero-padded)

typedef _Float16 h2 __attribute__((ext_vector_type(2)));
typedef _Float16 h8 __attribute__((ext_vector_type(8)));
typedef float f4 __attribute__((ext_vector_type(4)));

__device__ __forceinline__ uint32_t pack2u(float x, float y) {
    h2 p; p.x = (_Float16)x; p.y = (_Float16)y;
    return __builtin_bit_cast(uint32_t, p);
}

// ---------------------------------------------------------------------------
// Phase A: in1_ff[bt,h] = X[bt,:] . W_ih1[h,:] + b_ih1[h]
// M=64000, N=128, K=700(pad 704). f16 MFMA 16x16x32 (verified r12). FROZEN.
// ---------------------------------------------------------------------------
__global__ __launch_bounds__(256) void ff_gemm(const float* __restrict__ X,
                                               const float* __restrict__ W,
                                               const float* __restrict__ bias,
                                               float* __restrict__ out) {
    __shared__ __align__(16) uint32_t Xs[2][128][16];   // 8 KB x2 (f16 pairs)
    __shared__ __align__(16) uint32_t Ws[2][128][16];   // 8 KB x2
    const int tid   = threadIdx.x;
    const int w     = tid >> 6;
    const int lane  = tid & 63;
    const int m0    = blockIdx.x * 128;
    const int srow  = tid & 127;
    const int shalf = tid >> 7;
    const int lr    = lane & 15;
    const int lg    = lane >> 4;

    f4 acc[2][8];
#pragma unroll
    for (int m = 0; m < 2; ++m)
#pragma unroll
        for (int n = 0; n < 8; ++n) acc[m][n] = (f4){0.f, 0.f, 0.f, 0.f};

    float4 x4[4], w4[4];

#define LOADT(t)                                                               \
    {                                                                          \
        const int k0 = (t) * 32 + shalf * 16;                                  \
        if ((t) < 21 || shalf == 0) {                                          \
            _Pragma("unroll")                                                  \
            for (int q = 0; q < 4; ++q) {                                      \
                x4[q] = *(const float4*)&X[(size_t)(m0 + srow) * GK + k0 + q * 4]; \
                w4[q] = *(const float4*)&W[(size_t)srow * GK + k0 + q * 4];    \
            }                                                                  \
        } else {                                                               \
            _Pragma("unroll")                                                  \
            for (int q = 0; q < 3; ++q) {                                      \
                x4[q] = *(const float4*)&X[(size_t)(m0 + srow) * GK + k0 + q * 4]; \
                w4[q] = *(const float4*)&W[(size_t)srow * GK + k0 + q * 4];    \
            }                                                                  \
            x4[3] = (float4){0.f, 0.f, 0.f, 0.f};                              \
            w4[3] = (float4){0.f, 0.f, 0.f, 0.f};                              \
        }                                                                      \
    }
#define STORET(buf)                                                            \
    {                                                                          \
        _Pragma("unroll")                                                      \
        for (int q = 0; q < 4; ++q) {                                          \
            Xs[buf][srow][shalf * 8 + 2 * q]     = pack2u(x4[q].x, x4[q].y);   \
            Xs[buf][srow][shalf * 8 + 2 * q + 1] = pack2u(x4[q].z, x4[q].w);   \
            Ws[buf][srow][shalf * 8 + 2 * q]     = pack2u(w4[q].x, w4[q].y);   \
            Ws[buf][srow][shalf * 8 + 2 * q + 1] = pack2u(w4[q].z, w4[q].w);   \
        }                                                                      \
    }

    LOADT(0);
    STORET(0);
    __syncthreads();
    int cur = 0;
    for (int t = 0; t < NKT; ++t) {
        if (t + 1 < NKT) LOADT(t + 1);
        h8 a[2];
#pragma unroll
        for (int m = 0; m < 2; ++m) {
            const uint4 au = *(const uint4*)&Xs[cur][w * 32 + m * 16 + lr][lg * 4];
            a[m] = __builtin_bit_cast(h8, au);
        }
#pragma unroll
        for (int n = 0; n < 8; ++n) {
            const uint4 bu = *(const uint4*)&Ws[cur][n * 16 + lr][lg * 4];
            const h8 bf = __builtin_bit_cast(h8, bu);
            acc[0][n] = __builtin_amdgcn_mfma_f32_16x16x32_f16(a[0], bf, acc[0][n], 0, 0, 0);
            acc[1][n] = __builtin_amdgcn_mfma_f32_16x16x32_f16(a[1], bf, acc[1][n], 0, 0, 0);
        }
        if (t + 1 < NKT) STORET(cur ^ 1);
        __syncthreads();
        cur ^= 1;
    }

    float bv[8];
#pragma unroll
    for (int n = 0; n < 8; ++n) bv[n] = bias[n * 16 + lr];
#pragma unroll
    for (int m = 0; m < 2; ++m)
#pragma unroll
        for (int q = 0; q < 4; ++q) {
            const size_t row = (size_t)(m0 + w * 32 + m * 16 + lg * 4 + q);
#pragma unroll
            for (int n = 0; n < 8; ++n)
                out[row * HN + n * 16 + lr] = acc[m][n][q] + bv[n];
        }
#undef LOADT
#undef STORET
}

// ---------------------------------------------------------------------------
// helpers for the recurrence
// ---------------------------------------------------------------------------
// quantize one 128-float row from global into 8 uint4 REGISTERS + scale
__device__ __forceinline__ void qrow(const float* __restrict__ src,
                                     uint4 (&wq)[8], float& sc) {
    float amax = 0.f;
#pragma unroll
    for (int q = 0; q < 32; ++q) {
        float4 v = *(const float4*)&src[q * 4];
        amax = fmaxf(amax, fmaxf(fmaxf(fabsf(v.x), fabsf(v.y)),
                                 fmaxf(fabsf(v.z), fabsf(v.w))));
    }
    const float qs = (amax > 0.f) ? 127.f / amax : 0.f;
#pragma unroll
    for (int g = 0; g < 8; ++g) {
        uint32_t u[4];
#pragma unroll
        for (int e = 0; e < 4; ++e) {
            float4 v = *(const float4*)&src[g * 16 + e * 4];
            const int q0 = (int)rintf(v.x * qs), q1 = (int)rintf(v.y * qs);
            const int q2 = (int)rintf(v.z * qs), q3 = (int)rintf(v.w * qs);
            u[e] = (uint32_t)(q0 & 255) | ((uint32_t)(q1 & 255) << 8) |
                   ((uint32_t)(q2 & 255) << 16) | ((uint32_t)(q3 & 255) << 24);
        }
        wq[g].x = u[0]; wq[g].y = u[1]; wq[g].z = u[2]; wq[g].w = u[3];
    }
    sc = (amax > 0.f) ? amax / 127.f : 0.f;
}

// 128-dot: register weights vs wave-uniform packed spike bytes; 4 chains
__device__ __forceinline__ int mvqr(const uint4 (&wq)[8], const uint4 (&sv)[8]) {
    int a0 = 0, a1 = 0, a2 = 0, a3 = 0;
#pragma unroll
    for (int g = 0; g < 8; ++g) {
        a0 = __builtin_amdgcn_sdot4((int)wq[g].x, (int)sv[g].x, a0, false);
        a1 = __builtin_amdgcn_sdot4((int)wq[g].y, (int)sv[g].y, a1, false);
        a2 = __builtin_amdgcn_sdot4((int)wq[g].z, (int)sv[g].z, a2, false);
        a3 = __builtin_amdgcn_sdot4((int)wq[g].w, (int)sv[g].w, a3, false);
    }
    return (a0 + a1) + (a2 + a3);
}

#define LOADQ(arr, buf, sv)                                                    \
    {                                                                          \
        const uint4* _p = (const uint4*)&arr[buf][0];                          \
        _Pragma("unroll") for (int _g = 0; _g < 8; ++_g) sv[_g] = _p[_g];      \
    }

// ballot-mask nibble -> 4 packed 0/1 bytes
__device__ __forceinline__ uint32_t nib2bytes(uint32_t nib) {
    return ((nib & 15u) * 0x00204081u) & 0x01010101u;
}

// ---------------------------------------------------------------------------
// Phase B: register-weight sdot4 pipeline. One WG (512 thr, 8 waves) per
// batch row. Each heavy lane holds its quantized weight row in 8 uint4 REGS
// (loop-invariant -> zero weight LDS traffic; LDS only carries 128-bit spike
// words + pB partials + rdot). Roles (slot i, one barrier each):
//   w0,w1: S1 -> s1(i)   w2,w3: B -> pB(i-1)   w4,w5: C+L2 -> s2(i-2)
//   w6: RO -> rdot(i-3)  w7: OM -> om/softmax(i-4)
// ---------------------------------------------------------------------------
__global__ __launch_bounds__(512) void srnn_pipe11(
    const float* __restrict__ ff,
    const float* __restrict__ W_h1h1, const float* __restrict__ b_h1h1,
    const float* __restrict__ W_h1h2, const float* __restrict__ b_h1h2,
    const float* __restrict__ W_h2h2, const float* __restrict__ b_h2h2,
    const float* __restrict__ W_h2o,  const float* __restrict__ b_h2o,
    const float* __restrict__ tau_adp_h1, const float* __restrict__ tau_adp_h2,
    const float* __restrict__ tau_m_h1,   const float* __restrict__ tau_m_h2,
    const float* __restrict__ tau_m_o,
    const float* __restrict__ h1m0, const float* __restrict__ h2m0,
    const float* __restrict__ om0,
    float* __restrict__ out) {
    const int b    = blockIdx.x;
    const int tid  = threadIdx.x;
    const int w    = tid >> 6;
    const int lane = tid & 63;

    __shared__ __align__(16) uint32_t s1w[2][32];
    __shared__ __align__(16) uint32_t s2w[2][32];
    __shared__ float pBbuf[2][HN];
    __shared__ __align__(16) float rdot_lds[2][32];

    if (tid < 32) {
        s1w[0][tid] = 0u; s1w[1][tid] = 0u;
        s2w[0][tid] = 0u; s2w[1][tid] = 0u;
    }
    __syncthreads();

    if (w < 2) {
        // ================= S1: layer-1 LIF, j = w*64+lane =================
        const int j = (w << 6) + lane;
        uint4 wq[8]; float sA;
        qrow(W_h1h1 + j * HN, wq, sA);
        float h1m = h1m0[b * HN + j];
        const float a1 = expf(-1.f / tau_m_h1[j]);
        const float r1 = expf(-1.f / tau_adp_h1[j]);
        const float bi = b_h1h1[j];
        float b1 = 0.01f, s1p = 0.f;
        const float* fp = ff + (size_t)b * TSTEPS * HN + j;
        float fc = fp[0], fn = fp[HN];
        for (int i = 0; i < TSTEPS + 4; ++i) {
            if (i < TSTEPS) {
                const float f2 = (i + 2 < TSTEPS) ? fp[(size_t)(i + 2) * HN] : 0.f;
                uint4 sv[8];
                LOADQ(s1w, (i + 1) & 1, sv);               // s1(i-1)
                const float pA = sA * (float)mvqr(wq, sv);
                b1 = r1 * b1 + (1.f - r1) * s1p;
                const float Bt = 0.01f + 1.8f * b1;
                h1m = h1m * a1 + (1.f - a1) * (fc + bi + pA) - Bt * s1p;
                const int sp = (h1m - Bt > 0.f) ? 1 : 0;
                s1p = (float)sp;
                const unsigned long long mk = __ballot(sp);
                const uint32_t mlo = (uint32_t)mk, mhi = (uint32_t)(mk >> 32);
                if (lane < 16) {
                    const uint32_t nib = (lane < 8 ? mlo : mhi) >> ((lane & 7) * 4);
                    s1w[i & 1][(w << 4) + lane] = nib2bytes(nib);
                }
                fc = fn; fn = f2;
            }
            __syncthreads();
        }
    } else if (w < 4) {
        // ================= B: pB(i-1) = W_h1h2 . s1(i-1) =================
        const int j = ((w - 2) << 6) + lane;
        uint4 wq[8]; float sB;
        qrow(W_h1h2 + j * HN, wq, sB);
        for (int i = 0; i < TSTEPS + 4; ++i) {
            if (i >= 1 && i <= TSTEPS) {
                uint4 sv[8];
                LOADQ(s1w, (i - 1) & 1, sv);
                pBbuf[(i - 1) & 1][j] = sB * (float)mvqr(wq, sv);
            }
            __syncthreads();
        }
    } else if (w < 6) {
        // ================= C + LIF2: s2(i-2), j = (w-4)*64+lane ============
        const int j = ((w - 4) << 6) + lane;
        uint4 wq[8]; float sC;
        qrow(W_h2h2 + j * HN, wq, sC);
        float h2m = h2m0[b * HN + j];
        const float a2 = expf(-1.f / tau_m_h2[j]);
        const float r2 = expf(-1.f / tau_adp_h2[j]);
        const float bi = b_h1h2[j] + b_h2h2[j];
        float b2v = 0.01f, s2p = 0.f;
        for (int i = 0; i < TSTEPS + 4; ++i) {
            if (i >= 2 && i <= TSTEPS + 1) {
                const int k2 = i - 2;
                uint4 sv[8];
                LOADQ(s2w, (k2 + 1) & 1, sv);              // s2(k2-1)
                const float pC = sC * (float)mvqr(wq, sv);
                const float in2 = pBbuf[k2 & 1][j] + pC + bi;
                b2v = r2 * b2v + (1.f - r2) * s2p;
                const float Bt = 0.01f + 1.8f * b2v;
                h2m = h2m * a2 + (1.f - a2) * in2 - Bt * s2p;
                const int sp = (h2m - Bt > 0.f) ? 1 : 0;
                s2p = (float)sp;
                const unsigned long long mk = __ballot(sp);
                const uint32_t mlo = (uint32_t)mk, mhi = (uint32_t)(mk >> 32);
                if (lane < 16) {
                    const uint32_t nib = (lane < 8 ? mlo : mhi) >> ((lane & 7) * 4);
                    s2w[k2 & 1][((w - 4) << 4) + lane] = nib2bytes(nib);
                }
            }
            __syncthreads();
        }
    } else if (w == 6) {
        // ================= RO: rdot(i-3) = W_h2o . s2(i-3) =================
        const int o = lane;
        uint4 wq[8]; float sO;
        qrow(W_h2o + (size_t)((o < ON) ? o : 0) * HN, wq, sO);
        if (o >= ON) sO = 0.f;
        for (int i = 0; i < TSTEPS + 4; ++i) {
            if (i >= 3 && i <= TSTEPS + 2 && o < ON) {
                const int k3 = i - 3;
                uint4 sv[8];
                LOADQ(s2w, k3 & 1, sv);
                rdot_lds[k3 & 1][o] = sO * (float)mvqr(wq, sv);
            }
            __syncthreads();
        }
    } else {
        // ================= OM: redundant register softmax, no cross-lane ===
        float omv[ON], accv[ON], aov[ON], bov[ON];
#pragma unroll
        for (int k = 0; k < ON; ++k) {
            omv[k]  = om0[b * ON + k];
            aov[k]  = expf(-1.f / tau_m_o[k]);
            bov[k]  = b_h2o[k];
            accv[k] = 0.f;
        }
        for (int i = 0; i < TSTEPS + 4; ++i) {
            if (i >= 4) {
                const int k4 = i - 4;
                const float4* rp = (const float4*)&rdot_lds[k4 & 1][0];
                const float4 r0 = rp[0], r1 = rp[1], r2 = rp[2], r3 = rp[3], r4 = rp[4];
                float rd[ON];
                rd[0] = r0.x;  rd[1] = r0.y;  rd[2] = r0.z;  rd[3] = r0.w;
                rd[4] = r1.x;  rd[5] = r1.y;  rd[6] = r1.z;  rd[7] = r1.w;
                rd[8] = r2.x;  rd[9] = r2.y;  rd[10] = r2.z; rd[11] = r2.w;
                rd[12] = r3.x; rd[13] = r3.y; rd[14] = r3.z; rd[15] = r3.w;
                rd[16] = r4.x; rd[17] = r4.y; rd[18] = r4.z; rd[19] = r4.w;
#pragma unroll
                for (int k = 0; k < ON; ++k)
                    omv[k] = omv[k] * aov[k] + (1.f - aov[k]) * (rd[k] + bov[k]);
                float m0 = omv[0], m1 = omv[1], m2 = omv[2], m3 = omv[3];
#pragma unroll
                for (int k = 4; k < ON; k += 4) {
                    m0 = fmaxf(m0, omv[k]);
                    m1 = fmaxf(m1, omv[k + 1]);
                    m2 = fmaxf(m2, omv[k + 2]);
                    m3 = fmaxf(m3, omv[k + 3]);
                }
                const float mx = fmaxf(fmaxf(m0, m1), fmaxf(m2, m3));
                float e[ON];
                float d0 = 0.f, d1 = 0.f, d2 = 0.f, d3 = 0.f;
#pragma unroll
                for (int k = 0; k < ON; k += 4) {
                    e[k]     = __expf(omv[k] - mx);     d0 += e[k];
                    e[k + 1] = __expf(omv[k + 1] - mx); d1 += e[k + 1];
                    e[k + 2] = __expf(omv[k + 2] - mx); d2 += e[k + 2];
                    e[k + 3] = __expf(omv[k + 3] - mx); d3 += e[k + 3];
                }
                const float den = (d0 + d1) + (d2 + d3);
                if (k4 > 10) {
                    const float rden = 1.f / den;
#pragma unroll
                    for (int k = 0; k < ON; ++k)
                        accv[k] = fmaf(e[k], rden, accv[k]);
                }
            }
            __syncthreads();
        }
        if (lane == 0) {
#pragma unroll
            for (int k = 0; k < ON; ++k) out[b * ON + k] = accv[k];
        }
    }
}

// ---------------------------------------------------------------------------
// Phase C: A_norm = sum|W_h1h1| + sum|W_h2h2|  -> out[5120]  (exact fp32)
// ---------------------------------------------------------------------------
__global__ void anorm_kernel(const float* __restrict__ W1,
                             const float* __restrict__ W2,
                             float* __restrict__ out) {
    __shared__ float red[256];
    float s = 0.f;
    for (int i = threadIdx.x; i < HN * HN; i += 256)
        s += fabsf(W1[i]) + fabsf(W2[i]);
    red[threadIdx.x] = s;
    __syncthreads();
    for (int off = 128; off > 0; off >>= 1) {
        if (threadIdx.x < off) red[threadIdx.x] += red[threadIdx.x + off];
        __syncthreads();
    }
    if (threadIdx.x == 0) out[256 * ON] = red[0];
}

extern "C" void kernel_launch(void* const* d_in, const int* in_sizes, int n_in,
                              void* d_out, int out_size, void* d_ws, size_t ws_size,
                              hipStream_t stream) {
    const float* input      = (const float*)d_in[0];
    // d_in[1], d_in[2]: A1_mask/A2_mask -- all-ones, unused by reference math
    const float* W_ih1      = (const float*)d_in[3];
    const float* b_ih1      = (const float*)d_in[4];
    const float* W_h1h1     = (const float*)d_in[5];
    const float* b_h1h1     = (const float*)d_in[6];
    const float* W_h1h2     = (const float*)d_in[7];
    const float* b_h1h2     = (const float*)d_in[8];
    const float* W_h2h2     = (const float*)d_in[9];
    const float* b_h2h2     = (const float*)d_in[10];
    const float* W_h2o      = (const float*)d_in[11];
    const float* b_h2o      = (const float*)d_in[12];
    const float* tau_adp_h1 = (const float*)d_in[13];
    const float* tau_adp_h2 = (const float*)d_in[14];
    const float* tau_m_h1   = (const float*)d_in[15];
    const float* tau_m_h2   = (const float*)d_in[16];
    const float* tau_m_o    = (const float*)d_in[17];
    const float* h1m0       = (const float*)d_in[18];
    const float* h2m0       = (const float*)d_in[19];
    const float* om0        = (const float*)d_in[20];

    float* out   = (float*)d_out;
    float* ffbuf = (float*)d_ws;   // 256*250*128*4 = 32.768 MB

    anorm_kernel<<<1, 256, 0, stream>>>(W_h1h1, W_h2h2, out);
    ff_gemm<<<500, 256, 0, stream>>>(input, W_ih1, b_ih1, ffbuf);
    srnn_pipe11<<<256, 512, 0, stream>>>(ffbuf, W_h1h1, b_h1h1, W_h1h2, b_h1h2,
                                         W_h2h2, b_h2h2, W_h2o, b_h2o,
                                         tau_adp_h1, tau_adp_h2,
                                         tau_m_h1, tau_m_h2, tau_m_o,
                                         h1m0, h2m0, om0, out);
}